// Round 6
// baseline (798.918 us; speedup 1.0000x reference)
//
#include <hip/hip_runtime.h>
#include <math.h>

// Problem constants (from reference)
#define N_TOK 8192
#define DIM   4096
#define NEXP  64
#define CAP   160                        // ceil(1.25*8192/64)
#define OFF_CW    (83886080ULL)          // N_TOK*NEXP*CAP (floats)
#define OFF_PROBS (167772160ULL)
#define OFF_LOSS  (168296448ULL)         // OFF_PROBS + N_TOK*NEXP
#define NA    16384                      // N_TOK * K
#define TB    32                         // tokens per block (fused kernel)
#define KQ    1024                       // K-range per wave (DIM/4)

typedef short  bf16x8 __attribute__((ext_vector_type(8)));   // 8 bf16 = 4 VGPR
typedef float  f32x4  __attribute__((ext_vector_type(4)));   // MFMA acc

// fp32 -> bf16 round-to-nearest-even (bit trick; inputs are finite gaussians)
__device__ __forceinline__ unsigned short f2bf(float f) {
    unsigned int u = __float_as_uint(f);
    return (unsigned short)((u + 0x7FFFu + ((u >> 16) & 1u)) >> 16);
}
__device__ __forceinline__ float bf2f(unsigned short h) {
    return __uint_as_float(((unsigned int)h) << 16);
}
// split 8 fp32 into hi/lo bf16 frags (all indices compile-time after unroll)
__device__ __forceinline__ void split8(const float4 a0, const float4 a1,
                                       bf16x8& h, bf16x8& l) {
    const float v[8] = {a0.x, a0.y, a0.z, a0.w, a1.x, a1.y, a1.z, a1.w};
    #pragma unroll
    for (int e = 0; e < 8; ++e) {
        const unsigned short hh = f2bf(v[e]);
        h[e] = (short)hh;
        l[e] = (short)f2bf(v[e] - bf2f(hh));
    }
}

// ---------------- wave (64-lane) reductions ----------------
__device__ __forceinline__ float wave_max64(float v) {
    for (int m = 1; m < 64; m <<= 1) v = fmaxf(v, __shfl_xor(v, m, 64));
    return v;
}
__device__ __forceinline__ float wave_sum64(float v) {
    for (int m = 1; m < 64; m <<= 1) v += __shfl_xor(v, m, 64);
    return v;
}
// argmax with tie-break to LOWEST index (matches lax.top_k stability)
__device__ __forceinline__ void wave_argmax64(float& v, int& i) {
    for (int m = 1; m < 64; m <<= 1) {
        float ov = __shfl_xor(v, m, 64);
        int   oi = __shfl_xor(i, m, 64);
        if (ov > v || (ov == v && oi < i)) { v = ov; i = oi; }
    }
}

// ---------------- K1: fused split-bf16 MFMA GEMM + softmax/top-2 router --------
// 256 blocks x 256 thr. Block b: tokens [b*32, b*32+32), all 64 experts, FULL
// K=4096 (wave wv owns K-quarter wv*1024..+1024; 32 chunks of 32).
// logits = xh*wh + xl*wh + xh*wl (xl*wl ~2^-18 rel, dropped) — byte-identical
// math to the round-5 accepted GEMM; B is split from fp32 gw in-register (same
// L2 bytes as pre-split bf16 hi+lo, kills the k_wsplit kernel).
// Cross-wave K-reduction in LDS, then router (softmax + top-2 + probs + rec)
// runs in-block: the 16.8MB part round-trip, k_router and k_preduce launches
// all disappear. psum via 64 atomicAdds/block (fp reorder noise ~1e-6 on the
// loss only). x read exactly once: 134MB -> 21us HBM floor for the whole K1.
__global__ __launch_bounds__(256) void k_fused(const float* __restrict__ x,
                                               const float* __restrict__ gw,
                                               float* __restrict__ probs_out,
                                               int* __restrict__ rec_e,
                                               float* __restrict__ rec_w,
                                               float* __restrict__ psum_g) {
    __shared__ float lsum[4 * TB * 65];           // 4 waves x 32 tok x 65 (pad)
    const int t    = threadIdx.x;
    const int wv   = t >> 6;
    const int lane = t & 63;
    const int r16  = lane & 15;
    const int hi4  = lane >> 4;
    const int kro  = hi4 * 8;
    const int tokb = blockIdx.x * TB;
    const int kb   = wv * KQ;

    f32x4 acc[2][4];
    #pragma unroll
    for (int i = 0; i < 2; ++i)
        #pragma unroll
        for (int j = 0; j < 4; ++j) acc[i][j] = (f32x4){0.f, 0.f, 0.f, 0.f};

    for (int c = 0; c < KQ / 32; ++c) {           // 32 chunks
        const size_t k0 = (size_t)kb + c * 32 + kro;
        // B fragments: load fp32 gw, split in-register (L2-resident, 1MB)
        bf16x8 bhf[4], blf[4];
        #pragma unroll
        for (int j = 0; j < 4; ++j) {
            const float* gp = gw + (size_t)(j * 16 + r16) * DIM + k0;
            split8(*(const float4*)gp, *(const float4*)(gp + 4), bhf[j], blf[j]);
        }
        // A tiles (2 x 16 tokens): load 8 fp32 from x, split, 12 MFMA each
        #pragma unroll
        for (int i = 0; i < 2; ++i) {
            const float* ap = x + (size_t)(tokb + i * 16 + r16) * DIM + k0;
            bf16x8 ah, al;
            split8(*(const float4*)ap, *(const float4*)(ap + 4), ah, al);
            #pragma unroll
            for (int j = 0; j < 4; ++j) {
                acc[i][j] = __builtin_amdgcn_mfma_f32_16x16x32_bf16(ah, bhf[j], acc[i][j], 0, 0, 0);
                acc[i][j] = __builtin_amdgcn_mfma_f32_16x16x32_bf16(al, bhf[j], acc[i][j], 0, 0, 0);
                acc[i][j] = __builtin_amdgcn_mfma_f32_16x16x32_bf16(ah, blf[j], acc[i][j], 0, 0, 0);
            }
        }
    }
    // Phase A: spill partials. D layout: tok = i*16 + hi4*4 + r, exp = j*16 + r16
    #pragma unroll
    for (int i = 0; i < 2; ++i)
        #pragma unroll
        for (int j = 0; j < 4; ++j)
            #pragma unroll
            for (int r = 0; r < 4; ++r)
                lsum[wv * (TB * 65) + (i * 16 + hi4 * 4 + r) * 65 + (j * 16 + r16)] =
                    acc[i][j][r];
    __syncthreads();
    // Phase B: reduce the 4 K-quarters (stride-256 flat -> conflict-free)
    for (int f = t; f < TB * 64; f += 256) {
        const int o = (f >> 6) * 65 + (f & 63);
        lsum[o] = lsum[o] + lsum[TB * 65 + o] + lsum[2 * TB * 65 + o] +
                  lsum[3 * TB * 65 + o];
    }
    __syncthreads();
    // Phase C: router — wave wv handles tokens wv*8 .. wv*8+7
    float colsum = 0.f;                           // per lane: sum p over my tokens, expert=lane
    for (int q = 0; q < 8; ++q) {
        const int tok = wv * 8 + q;
        const float l  = lsum[tok * 65 + lane];
        const float m  = wave_max64(l);
        const float ex = expf(l - m);
        const float sm = wave_sum64(ex);
        const float p  = ex / sm;
        probs_out[(size_t)(tokb + tok) * NEXP + lane] = p;
        colsum += p;
        float v1 = p; int i1 = lane;
        wave_argmax64(v1, i1);
        float v2 = (lane == i1) ? -1.f : p; int i2 = lane;
        wave_argmax64(v2, i2);
        if (lane == 0) {
            const int gt = tokb + tok;
            const float denom = v1 + v2;
            rec_e[2 * gt]     = i1;
            rec_e[2 * gt + 1] = i2;
            rec_w[2 * gt]     = v1 / denom;
            rec_w[2 * gt + 1] = v2 / denom;
        }
    }
    __syncthreads();                              // all Phase-C LDS reads done
    // Phase D: block-local probs column sums -> one atomicAdd per expert
    lsum[wv * 64 + lane] = colsum;
    __syncthreads();
    if (t < 64)
        atomicAdd(psum_g + t,
                  lsum[t] + lsum[64 + t] + lsum[128 + t] + lsum[192 + t]);
}

// ---------------- K2: slot assignment + inline scatter + loss ----------------
// Blocks 0..15 (64 waves): wave w owns expert w; scans the 16384 flat
// assignments in token-major order (matching the reference cumsum) in 256
// ballot rounds. Kept assignments are written straight into the harness-zeroed
// output (unique (tok,e,slot) per expert -> no collisions). Block 16:
// per-expert totals via LDS histogram + load-balance loss (psum_g direct).
__global__ __launch_bounds__(256) void k_assign_scatter(const int* __restrict__ rec_e,
                                                        const float* __restrict__ rec_w,
                                                        const float* __restrict__ psum_g,
                                                        float* __restrict__ out) {
    if (blockIdx.x == 16) {
        __shared__ int hcnt[64];
        if (threadIdx.x < 64) hcnt[threadIdx.x] = 0;
        __syncthreads();
        for (int j = 0; j < 64; ++j) {
            const int e = rec_e[j * 256 + threadIdx.x];
            atomicAdd(&hcnt[e], 1);
        }
        __syncthreads();
        if (threadIdx.x < 64) {
            const int e = threadIdx.x;
            float term = ((float)hcnt[e] / (float)NA) * (psum_g[e] / (float)N_TOK);
            term = wave_sum64(term);
            if (e == 0) out[OFF_LOSS] = 0.01f * 64.f * term;
        }
        return;
    }
    const int w    = blockIdx.x * 4 + (threadIdx.x >> 6);   // expert id
    const int lane = threadIdx.x & 63;
    int base = 0;
    const unsigned long long ltmask = (1ull << lane) - 1ull;
    #pragma unroll 4
    for (int c = 0; c < NA / 64; ++c) {
        const int i = c * 64 + lane;
        const int e = rec_e[i];
        const unsigned long long mask = __ballot(e == w);
        if (e == w) {
            const int slot = base + __popcll(mask & ltmask);
            if (slot < CAP) {
                const int tok = i >> 1;
                const size_t off = (size_t)tok * (NEXP * CAP) + (size_t)w * CAP + slot;
                out[off]          = 1.0f;
                out[OFF_CW + off] = rec_w[i];
            }
        }
        base += __popcll(mask);
    }
}

extern "C" void kernel_launch(void* const* d_in, const int* in_sizes, int n_in,
                              void* d_out, int out_size, void* d_ws, size_t ws_size,
                              hipStream_t stream) {
    const float* x  = (const float*)d_in[0];
    const float* gw = (const float*)d_in[1];
    float* out = (float*)d_out;

    char* w = (char*)d_ws;
    int*   rec_e  = (int*)w;
    float* rec_w  = (float*)(w + NA * 4);
    float* psum_g = (float*)(w + 2 * NA * 4);

    hipMemsetAsync(psum_g, 0, NEXP * sizeof(float), stream);
    k_fused<<<256, 256, 0, stream>>>(x, gw, out + OFF_PROBS, rec_e, rec_w, psum_g);
    k_assign_scatter<<<17, 256, 0, stream>>>(rec_e, rec_w, psum_g, out);
}

// Round 7
// 756.318 us; speedup vs baseline: 1.0563x; 1.0563x over previous
//
#include <hip/hip_runtime.h>
#include <math.h>

// Problem constants (from reference)
#define N_TOK 8192
#define DIM   4096
#define NEXP  64
#define CAP   160                        // ceil(1.25*8192/64)
#define OFF_CW    (83886080ULL)          // N_TOK*NEXP*CAP (floats)
#define OFF_PROBS (167772160ULL)
#define OFF_LOSS  (168296448ULL)         // OFF_PROBS + N_TOK*NEXP
#define NA    16384                      // N_TOK * K
#define SPLIT 8                          // K-split for GEMM (part slices)
#define KSL   (DIM / SPLIT)              // 512 d per k-slice
#define CHUNKS (KSL / 32)                // 16 MFMA k-chunks per slice

typedef short  bf16x8 __attribute__((ext_vector_type(8)));   // 8 bf16 = 4 VGPR
typedef float  f32x4  __attribute__((ext_vector_type(4)));   // MFMA acc

// fp32 -> bf16 round-to-nearest-even (bit trick; inputs are finite gaussians)
__device__ __forceinline__ unsigned short f2bf(float f) {
    unsigned int u = __float_as_uint(f);
    return (unsigned short)((u + 0x7FFFu + ((u >> 16) & 1u)) >> 16);
}
__device__ __forceinline__ float bf2f(unsigned short h) {
    return __uint_as_float(((unsigned int)h) << 16);
}
// split 8 fp32 into hi/lo bf16 frags (all indices compile-time after unroll)
__device__ __forceinline__ void split8(const float4 a0, const float4 a1,
                                       bf16x8& h, bf16x8& l) {
    const float v[8] = {a0.x, a0.y, a0.z, a0.w, a1.x, a1.y, a1.z, a1.w};
    #pragma unroll
    for (int e = 0; e < 8; ++e) {
        const unsigned short hh = f2bf(v[e]);
        h[e] = (short)hh;
        l[e] = (short)f2bf(v[e] - bf2f(hh));
    }
}

// ---------------- wave (64-lane) reductions ----------------
__device__ __forceinline__ float wave_max64(float v) {
    for (int m = 1; m < 64; m <<= 1) v = fmaxf(v, __shfl_xor(v, m, 64));
    return v;
}
__device__ __forceinline__ float wave_sum64(float v) {
    for (int m = 1; m < 64; m <<= 1) v += __shfl_xor(v, m, 64);
    return v;
}
// argmax with tie-break to LOWEST index (matches lax.top_k stability)
__device__ __forceinline__ void wave_argmax64(float& v, int& i) {
    for (int m = 1; m < 64; m <<= 1) {
        float ov = __shfl_xor(v, m, 64);
        int   oi = __shfl_xor(i, m, 64);
        if (ov > v || (ov == v && oi < i)) { v = ov; i = oi; }
    }
}

// ---------------- K0: split gate weights into hi/lo bf16 ----------------
// 64 blocks (one expert row each). 1MB fp32 -> 2x 512KB bf16; ~3us.
__global__ __launch_bounds__(256) void k_wsplit(const float* __restrict__ gw,
                                                unsigned short* __restrict__ wh,
                                                unsigned short* __restrict__ wl) {
    const float* src = gw + (size_t)blockIdx.x * DIM;
    unsigned short* dh = wh + (size_t)blockIdx.x * DIM;
    unsigned short* dl = wl + (size_t)blockIdx.x * DIM;
    for (int i = threadIdx.x; i < DIM / 4; i += 256) {
        const float4 v = *(const float4*)(src + 4 * i);
        ushort4 h, l;
        h.x = f2bf(v.x); l.x = f2bf(v.x - bf2f(h.x));
        h.y = f2bf(v.y); l.y = f2bf(v.y - bf2f(h.y));
        h.z = f2bf(v.z); l.z = f2bf(v.z - bf2f(h.z));
        h.w = f2bf(v.w); l.w = f2bf(v.w - bf2f(h.w));
        *(ushort4*)(dh + 4 * i) = h;
        *(ushort4*)(dl + 4 * i) = l;
    }
}

// ---------------- K1: split-bf16 MFMA logits GEMM (4 waves/SIMD re-tile) -------
// logits = xh*wh + xl*wh + xh*wl (xl*wl ~ 2^-18 relative, dropped).
// Round-5 math, re-tiled for occupancy: round 5 ran 1024 waves on 1024 SIMDs
// (1 wave/SIMD, zero TLP — every HBM/L2 load stall fully exposed). Now:
// wave = 16 tokens x 64 experts x 512 K (acc 1x4 f32x4, ~85 VGPR), grid =
// 128 token-blocks x 8 k-slices = 1024 blocks = 4096 waves = 4 waves/SIMD.
// Per-output accumulation order is byte-identical to round 5 (same chunk
// sequence, same 3-term MFMA order) -> absmax must reproduce 0.00390625.
// B redundancy: 512MB of L2 reads (wh/wl = 2MB, resident per-XCD) ~= 15us
// aggregate, hidden under the 134MB HBM x-stream (21us floor).
__global__ __launch_bounds__(256) void k_gemm_mfma(const float* __restrict__ x,
                                                   const unsigned short* __restrict__ wh,
                                                   const unsigned short* __restrict__ wl,
                                                   float* __restrict__ part) {
    const int sy   = blockIdx.x >> 7;               // k-slice 0..7
    const int tbk  = blockIdx.x & 127;              // token-block (64 tokens)
    const int wv   = threadIdx.x >> 6;              // wave 0..3
    const int lane = threadIdx.x & 63;
    const int r16  = lane & 15;
    const int kro  = (lane >> 4) * 8;               // lane's k sub-offset
    const int tokb = tbk * 64 + wv * 16;            // this wave's 16 tokens

    f32x4 acc[4];
    #pragma unroll
    for (int j = 0; j < 4; ++j) acc[j] = (f32x4){0.f, 0.f, 0.f, 0.f};

    for (int c = 0; c < CHUNKS; ++c) {
        const size_t k0 = (size_t)sy * KSL + c * 32 + kro;
        // B fragments (hi+lo) for the 4 expert tiles — 16B L2 loads
        bf16x8 bhf[4], blf[4];
        #pragma unroll
        for (int j = 0; j < 4; ++j) {
            const size_t wo = (size_t)(j * 16 + r16) * DIM + k0;
            bhf[j] = *(const bf16x8*)(wh + wo);
            blf[j] = *(const bf16x8*)(wl + wo);
        }
        // A tile: load 8 fp32 from x, split once, 12 MFMA
        const float* ap = x + (size_t)(tokb + r16) * DIM + k0;
        const float4 a0 = *(const float4*)(ap);
        const float4 a1 = *(const float4*)(ap + 4);
        bf16x8 ah, al;
        split8(a0, a1, ah, al);
        #pragma unroll
        for (int j = 0; j < 4; ++j) {
            acc[j] = __builtin_amdgcn_mfma_f32_16x16x32_bf16(ah, bhf[j], acc[j], 0, 0, 0);
            acc[j] = __builtin_amdgcn_mfma_f32_16x16x32_bf16(al, bhf[j], acc[j], 0, 0, 0);
            acc[j] = __builtin_amdgcn_mfma_f32_16x16x32_bf16(ah, blf[j], acc[j], 0, 0, 0);
        }
    }
    // epilogue: D row=(lane>>4)*4+reg (token), col=lane&15 (expert)
    float* pb = part + (size_t)sy * N_TOK * NEXP;
    const int trow = tokb + (lane >> 4) * 4;
    #pragma unroll
    for (int j = 0; j < 4; ++j) {
        const int e = j * 16 + r16;
        #pragma unroll
        for (int r = 0; r < 4; ++r)
            pb[(size_t)(trow + r) * NEXP + e] = acc[j][r];
    }
}

// ---------------- K2: softmax + top-2 per token (wave per token) ----------------
__global__ __launch_bounds__(256) void k_router(const float* __restrict__ part,
                                                float* __restrict__ probs_out,
                                                int* __restrict__ rec_e,
                                                float* __restrict__ rec_w) {
    const int tok  = blockIdx.x * 4 + (threadIdx.x >> 6);
    const int lane = threadIdx.x & 63;
    float l = 0.f;
    for (int s = 0; s < SPLIT; ++s)
        l += part[(size_t)s * N_TOK * NEXP + (size_t)tok * NEXP + lane];
    const float m  = wave_max64(l);
    const float ex = expf(l - m);
    const float sm = wave_sum64(ex);
    const float p  = ex / sm;
    probs_out[(size_t)tok * NEXP + lane] = p;
    float v1 = p; int i1 = lane;
    wave_argmax64(v1, i1);
    float v2 = (lane == i1) ? -1.f : p; int i2 = lane;
    wave_argmax64(v2, i2);
    if (lane == 0) {
        const float denom = v1 + v2;
        rec_e[2 * tok]     = i1;
        rec_e[2 * tok + 1] = i2;
        rec_w[2 * tok]     = v1 / denom;
        rec_w[2 * tok + 1] = v2 / denom;
    }
}

// ---------------- K3: probs partial column sums (deterministic, no atomics) ----
__global__ __launch_bounds__(256) void k_preduce(const float* __restrict__ probs,
                                                 float* __restrict__ psum_part) {
    __shared__ float sh[256];
    const int e = threadIdx.x & 63, tg = threadIdx.x >> 6;
    const int tok0 = blockIdx.x * 128;
    float a = 0.f;
    for (int k = 0; k < 32; ++k)
        a += probs[(size_t)(tok0 + tg + 4 * k) * NEXP + e];
    sh[threadIdx.x] = a;
    __syncthreads();
    if (threadIdx.x < 64)
        psum_part[blockIdx.x * 64 + threadIdx.x] =
            sh[threadIdx.x] + sh[64 + threadIdx.x] +
            sh[128 + threadIdx.x] + sh[192 + threadIdx.x];
}

// ---------------- K4: slot assignment + inline scatter + loss ----------------
__global__ __launch_bounds__(256) void k_assign_scatter(const int* __restrict__ rec_e,
                                                        const float* __restrict__ rec_w,
                                                        const float* __restrict__ psum_part,
                                                        float* __restrict__ out) {
    if (blockIdx.x == 16) {
        __shared__ int hcnt[64];
        if (threadIdx.x < 64) hcnt[threadIdx.x] = 0;
        __syncthreads();
        for (int j = 0; j < 64; ++j) {
            const int e = rec_e[j * 256 + threadIdx.x];
            atomicAdd(&hcnt[e], 1);
        }
        __syncthreads();
        if (threadIdx.x < 64) {
            const int e = threadIdx.x;
            float ps = 0.f;
            for (int b = 0; b < 64; ++b) ps += psum_part[b * 64 + e];
            float term = ((float)hcnt[e] / (float)NA) * (ps / (float)N_TOK);
            term = wave_sum64(term);
            if (e == 0) out[OFF_LOSS] = 0.01f * 64.f * term;
        }
        return;
    }
    const int w    = blockIdx.x * 4 + (threadIdx.x >> 6);   // expert id
    const int lane = threadIdx.x & 63;
    int base = 0;
    const unsigned long long ltmask = (1ull << lane) - 1ull;
    #pragma unroll 4
    for (int c = 0; c < NA / 64; ++c) {
        const int i = c * 64 + lane;
        const int e = rec_e[i];
        const unsigned long long mask = __ballot(e == w);
        if (e == w) {
            const int slot = base + __popcll(mask & ltmask);
            if (slot < CAP) {
                const int tok = i >> 1;
                const size_t off = (size_t)tok * (NEXP * CAP) + (size_t)w * CAP + slot;
                out[off]          = 1.0f;
                out[OFF_CW + off] = rec_w[i];
            }
        }
        base += __popcll(mask);
    }
}

extern "C" void kernel_launch(void* const* d_in, const int* in_sizes, int n_in,
                              void* d_out, int out_size, void* d_ws, size_t ws_size,
                              hipStream_t stream) {
    const float* x  = (const float*)d_in[0];
    const float* gw = (const float*)d_in[1];
    float* out = (float*)d_out;

    char* w = (char*)d_ws;
    float* part      = (float*)w;                                      // 16.78MB
    int*   rec_e     = (int*)(w + (size_t)SPLIT * N_TOK * NEXP * 4);
    float* rec_w     = (float*)((char*)rec_e + NA * 4);
    float* psum_part = (float*)((char*)rec_w + NA * 4);
    unsigned short* wh = (unsigned short*)((char*)psum_part + 64 * 64 * 4);
    unsigned short* wl = wh + (size_t)NEXP * DIM;                      // +512KB each

    k_wsplit<<<64, 256, 0, stream>>>(gw, wh, wl);
    k_gemm_mfma<<<1024, 256, 0, stream>>>(x, wh, wl, part);
    k_router<<<2048, 256, 0, stream>>>(part, out + OFF_PROBS, rec_e, rec_w);
    k_preduce<<<64, 256, 0, stream>>>(out + OFF_PROBS, psum_part);
    k_assign_scatter<<<17, 256, 0, stream>>>(rec_e, rec_w, psum_part, out);
}

// Round 8
// 720.320 us; speedup vs baseline: 1.1091x; 1.0500x over previous
//
#include <hip/hip_runtime.h>
#include <math.h>

// Problem constants (from reference)
#define N_TOK 8192
#define DIM   4096
#define NEXP  64
#define CAP   160                        // ceil(1.25*8192/64)
#define OFF_CW    (83886080ULL)          // N_TOK*NEXP*CAP (floats)
#define OFF_PROBS (167772160ULL)
#define OFF_LOSS  (168296448ULL)         // OFF_PROBS + N_TOK*NEXP
#define NA    16384                      // N_TOK * K
#define SPLIT 8                          // K-split for GEMM (part slices)
#define KSL   (DIM / SPLIT)              // 512 d per k-slice
#define CHUNKS (KSL / 32)                // 16 MFMA k-chunks per slice
#define NRB   2048                       // router blocks (psum partials)

typedef short  bf16x8 __attribute__((ext_vector_type(8)));   // 8 bf16 = 4 VGPR
typedef float  f32x4  __attribute__((ext_vector_type(4)));   // MFMA acc

// fp32 -> bf16 round-to-nearest-even (bit trick; inputs are finite gaussians)
__device__ __forceinline__ unsigned short f2bf(float f) {
    unsigned int u = __float_as_uint(f);
    return (unsigned short)((u + 0x7FFFu + ((u >> 16) & 1u)) >> 16);
}
__device__ __forceinline__ float bf2f(unsigned short h) {
    return __uint_as_float(((unsigned int)h) << 16);
}
// split 8 fp32 into hi/lo bf16 frags (all indices compile-time after unroll)
__device__ __forceinline__ void split8(const float4 a0, const float4 a1,
                                       bf16x8& h, bf16x8& l) {
    const float v[8] = {a0.x, a0.y, a0.z, a0.w, a1.x, a1.y, a1.z, a1.w};
    #pragma unroll
    for (int e = 0; e < 8; ++e) {
        const unsigned short hh = f2bf(v[e]);
        h[e] = (short)hh;
        l[e] = (short)f2bf(v[e] - bf2f(hh));
    }
}

// ---------------- wave (64-lane) reductions ----------------
__device__ __forceinline__ float wave_max64(float v) {
    for (int m = 1; m < 64; m <<= 1) v = fmaxf(v, __shfl_xor(v, m, 64));
    return v;
}
__device__ __forceinline__ float wave_sum64(float v) {
    for (int m = 1; m < 64; m <<= 1) v += __shfl_xor(v, m, 64);
    return v;
}
// argmax with tie-break to LOWEST index (matches lax.top_k stability)
__device__ __forceinline__ void wave_argmax64(float& v, int& i) {
    for (int m = 1; m < 64; m <<= 1) {
        float ov = __shfl_xor(v, m, 64);
        int   oi = __shfl_xor(i, m, 64);
        if (ov > v || (ov == v && oi < i)) { v = ov; i = oi; }
    }
}

// ---------------- K0: split gate weights into hi/lo bf16 ----------------
// 64 blocks (one expert row each). 1MB fp32 -> 2x 512KB bf16; ~3us.
__global__ __launch_bounds__(256) void k_wsplit(const float* __restrict__ gw,
                                                unsigned short* __restrict__ wh,
                                                unsigned short* __restrict__ wl) {
    const float* src = gw + (size_t)blockIdx.x * DIM;
    unsigned short* dh = wh + (size_t)blockIdx.x * DIM;
    unsigned short* dl = wl + (size_t)blockIdx.x * DIM;
    for (int i = threadIdx.x; i < DIM / 4; i += 256) {
        const float4 v = *(const float4*)(src + 4 * i);
        ushort4 h, l;
        h.x = f2bf(v.x); l.x = f2bf(v.x - bf2f(h.x));
        h.y = f2bf(v.y); l.y = f2bf(v.y - bf2f(h.y));
        h.z = f2bf(v.z); l.z = f2bf(v.z - bf2f(h.z));
        h.w = f2bf(v.w); l.w = f2bf(v.w - bf2f(h.w));
        *(ushort4*)(dh + 4 * i) = h;
        *(ushort4*)(dl + 4 * i) = l;
    }
}

// ---------------- K1: split-bf16 MFMA logits GEMM (ROUND-5 PROVEN, verbatim) ---
// logits = xh*wh + xl*wh + xh*wl (xl*wl ~ 2^-18 relative, dropped).
// 256 blocks = 32 token-blocks x 8 k-slices; 4 waves/block, wave = 64tok x
// 64exp (4x4 grid of 16x16x32 MFMA tiles). Evidence from R6/R7: this wave
// shape is the local optimum — R7's 16-tok re-tile (4x B redundancy, 4x waves)
// regressed 34us; R6's in-loop B-split regressed 77us. Per-wave efficiency
// (MFMA per load, B reuse) binds, not occupancy. Do not re-roll.
__global__ __launch_bounds__(256) void k_gemm_mfma(const float* __restrict__ x,
                                                   const unsigned short* __restrict__ wh,
                                                   const unsigned short* __restrict__ wl,
                                                   float* __restrict__ part) {
    const int sy   = blockIdx.x >> 5;               // k-slice 0..7
    const int tb   = (blockIdx.x & 31) * 256;       // block token base
    const int wv   = (threadIdx.x >> 6);            // wave 0..3
    const int lane = threadIdx.x & 63;
    const int r16  = lane & 15;
    const int kro  = (lane >> 4) * 8;               // lane's k sub-offset
    const int tokb = tb + wv * 64;

    f32x4 acc[4][4];
    #pragma unroll
    for (int i = 0; i < 4; ++i)
        #pragma unroll
        for (int j = 0; j < 4; ++j) acc[i][j] = (f32x4){0.f, 0.f, 0.f, 0.f};

    for (int c = 0; c < CHUNKS; ++c) {
        const size_t k0 = (size_t)sy * KSL + c * 32 + kro;
        // B fragments (hi+lo) for the 4 expert tiles — 16B L2 loads
        bf16x8 bhf[4], blf[4];
        #pragma unroll
        for (int j = 0; j < 4; ++j) {
            const size_t wo = (size_t)(j * 16 + r16) * DIM + k0;
            bhf[j] = *(const bf16x8*)(wh + wo);
            blf[j] = *(const bf16x8*)(wl + wo);
        }
        // A tiles: load 8 fp32, split, 12 MFMA each
        #pragma unroll
        for (int i = 0; i < 4; ++i) {
            const float* ap = x + (size_t)(tokb + i * 16 + r16) * DIM + k0;
            const float4 a0 = *(const float4*)(ap);
            const float4 a1 = *(const float4*)(ap + 4);
            bf16x8 ah, al;
            split8(a0, a1, ah, al);
            #pragma unroll
            for (int j = 0; j < 4; ++j) {
                acc[i][j] = __builtin_amdgcn_mfma_f32_16x16x32_bf16(ah, bhf[j], acc[i][j], 0, 0, 0);
                acc[i][j] = __builtin_amdgcn_mfma_f32_16x16x32_bf16(al, bhf[j], acc[i][j], 0, 0, 0);
                acc[i][j] = __builtin_amdgcn_mfma_f32_16x16x32_bf16(ah, blf[j], acc[i][j], 0, 0, 0);
            }
        }
    }
    // epilogue: D row=(lane>>4)*4+reg (token), col=lane&15 (expert)
    float* pb = part + (size_t)sy * N_TOK * NEXP;
    #pragma unroll
    for (int i = 0; i < 4; ++i) {
        const int trow = tokb + i * 16 + (lane >> 4) * 4;
        #pragma unroll
        for (int j = 0; j < 4; ++j) {
            const int e = j * 16 + r16;
            #pragma unroll
            for (int r = 0; r < 4; ++r)
                pb[(size_t)(trow + r) * NEXP + e] = acc[i][j][r];
        }
    }
}

// ---------------- K2: softmax + top-2 + probs colsum (preduce folded in) -------
// 2048 blocks x 4 waves, 1 token per wave. Each lane ends with p(token, lane);
// block-local column sum over its 4 tokens -> deterministic psum_part[block][64]
// (no atomics, no ordering dependence). Kills the k_preduce launch + its 2MB
// probs re-read.
__global__ __launch_bounds__(256) void k_router(const float* __restrict__ part,
                                                float* __restrict__ probs_out,
                                                int* __restrict__ rec_e,
                                                float* __restrict__ rec_w,
                                                float* __restrict__ psum_part) {
    __shared__ float sh[256];
    const int wv   = threadIdx.x >> 6;
    const int tok  = blockIdx.x * 4 + wv;
    const int lane = threadIdx.x & 63;
    float l = 0.f;
    for (int s = 0; s < SPLIT; ++s)
        l += part[(size_t)s * N_TOK * NEXP + (size_t)tok * NEXP + lane];
    const float m  = wave_max64(l);
    const float ex = expf(l - m);
    const float sm = wave_sum64(ex);
    const float p  = ex / sm;
    probs_out[(size_t)tok * NEXP + lane] = p;
    float v1 = p; int i1 = lane;
    wave_argmax64(v1, i1);
    float v2 = (lane == i1) ? -1.f : p; int i2 = lane;
    wave_argmax64(v2, i2);
    if (lane == 0) {
        const float denom = v1 + v2;
        rec_e[2 * tok]     = i1;
        rec_e[2 * tok + 1] = i2;
        rec_w[2 * tok]     = v1 / denom;
        rec_w[2 * tok + 1] = v2 / denom;
    }
    // block colsum: psum_part[b][e] = sum over the block's 4 tokens of p[tok][e]
    sh[wv * 64 + lane] = p;
    __syncthreads();
    if (threadIdx.x < 64)
        psum_part[(size_t)blockIdx.x * 64 + threadIdx.x] =
            sh[threadIdx.x] + sh[64 + threadIdx.x] +
            sh[128 + threadIdx.x] + sh[192 + threadIdx.x];
}

// ---------------- K3: slot assignment + inline scatter + loss ----------------
// Blocks 0..15 (64 waves): wave w owns expert w; scans the 16384 flat
// assignments in token-major order (matching the reference cumsum) in 256
// ballot rounds. Kept assignments are written straight into the harness-zeroed
// output (unique (tok,e,slot) per expert -> no collisions). Block 16:
// per-expert totals via LDS histogram + load-balance loss (reduces the 2048
// router-block partials; runs concurrent with the scan blocks).
__global__ __launch_bounds__(256) void k_assign_scatter(const int* __restrict__ rec_e,
                                                        const float* __restrict__ rec_w,
                                                        const float* __restrict__ psum_part,
                                                        float* __restrict__ out) {
    if (blockIdx.x == 16) {
        __shared__ int hcnt[64];
        if (threadIdx.x < 64) hcnt[threadIdx.x] = 0;
        __syncthreads();
        for (int j = 0; j < 64; ++j) {
            const int e = rec_e[j * 256 + threadIdx.x];
            atomicAdd(&hcnt[e], 1);
        }
        __syncthreads();
        if (threadIdx.x < 64) {
            const int e = threadIdx.x;
            float ps = 0.f;
            for (int b = 0; b < NRB; ++b) ps += psum_part[(size_t)b * 64 + e];
            float term = ((float)hcnt[e] / (float)NA) * (ps / (float)N_TOK);
            term = wave_sum64(term);
            if (e == 0) out[OFF_LOSS] = 0.01f * 64.f * term;
        }
        return;
    }
    const int w    = blockIdx.x * 4 + (threadIdx.x >> 6);   // expert id
    const int lane = threadIdx.x & 63;
    int base = 0;
    const unsigned long long ltmask = (1ull << lane) - 1ull;
    #pragma unroll 4
    for (int c = 0; c < NA / 64; ++c) {
        const int i = c * 64 + lane;
        const int e = rec_e[i];
        const unsigned long long mask = __ballot(e == w);
        if (e == w) {
            const int slot = base + __popcll(mask & ltmask);
            if (slot < CAP) {
                const int tok = i >> 1;
                const size_t off = (size_t)tok * (NEXP * CAP) + (size_t)w * CAP + slot;
                out[off]          = 1.0f;
                out[OFF_CW + off] = rec_w[i];
            }
        }
        base += __popcll(mask);
    }
}

extern "C" void kernel_launch(void* const* d_in, const int* in_sizes, int n_in,
                              void* d_out, int out_size, void* d_ws, size_t ws_size,
                              hipStream_t stream) {
    const float* x  = (const float*)d_in[0];
    const float* gw = (const float*)d_in[1];
    float* out = (float*)d_out;

    char* w = (char*)d_ws;
    float* part      = (float*)w;                                      // 16.78MB
    int*   rec_e     = (int*)(w + (size_t)SPLIT * N_TOK * NEXP * 4);
    float* rec_w     = (float*)((char*)rec_e + NA * 4);
    float* psum_part = (float*)((char*)rec_w + NA * 4);                // 512KB
    unsigned short* wh = (unsigned short*)((char*)psum_part + (size_t)NRB * 64 * 4);
    unsigned short* wl = wh + (size_t)NEXP * DIM;                      // +512KB each

    k_wsplit<<<64, 256, 0, stream>>>(gw, wh, wl);
    k_gemm_mfma<<<256, 256, 0, stream>>>(x, wh, wl, part);
    k_router<<<2048, 256, 0, stream>>>(part, out + OFF_PROBS, rec_e, rec_w, psum_part);
    k_assign_scatter<<<17, 256, 0, stream>>>(rec_e, rec_w, psum_part, out);
}